// Round 6
// baseline (395.923 us; speedup 1.0000x reference)
//
#include <hip/hip_runtime.h>

#define T_STEPS 512
#define HSTRIDE 72     // shorts per LDS h-row (16B-aligned)
#define XSTRIDE 520    // _Float16 per x-row
#define OSTRIDE 513    // floats per out-row
#define NB 4           // batches per block -> 512 blocks = 2 independent blocks/CU

typedef short short8 __attribute__((ext_vector_type(8)));
typedef float f32x4 __attribute__((ext_vector_type(4)));
typedef _Float16 half4 __attribute__((ext_vector_type(4)));

#define K1 1.442695041f    // log2(e)
#define K2 2.885390082f    // 2*log2(e)

__device__ __forceinline__ float ex2(float x) {
#if __has_builtin(__builtin_amdgcn_exp2f)
    return __builtin_amdgcn_exp2f(x);
#else
    return exp2f(x);
#endif
}
__device__ __forceinline__ float rcp_fast(float x) {
#if __has_builtin(__builtin_amdgcn_rcpf)
    return __builtin_amdgcn_rcpf(x);
#else
    return 1.0f / x;
#endif
}
__device__ __forceinline__ unsigned short f2bf(float f) {
    union { float f; unsigned u; } v; v.f = f;
    unsigned r = v.u + 0x7fffu + ((v.u >> 16) & 1u);   // RNE
    return (unsigned short)(r >> 16);
}
__device__ __forceinline__ float bf2f(unsigned short b) {
    union { float f; unsigned u; } v; v.u = ((unsigned)b) << 16;
    return v.f;
}

// partial fc-dot over this lane's A-fragment slice, reduced over the 4 k-quads
__device__ __forceinline__ float out_dot(short8 a0, short8 a1,
                                         const float* wfc0, const float* wfc1) {
    float s = 0.f;
#pragma unroll
    for (int j = 0; j < 8; ++j) s = fmaf(bf2f((unsigned short)a0[j]), wfc0[j], s);
#pragma unroll
    for (int j = 0; j < 8; ++j) s = fmaf(bf2f((unsigned short)a1[j]), wfc1[j], s);
    s += __shfl_xor(s, 16);
    s += __shfl_xor(s, 32);
    return s;   // full 64-dot for batch row m = lane&15, on all lanes
}

// 256 thr = 4 waves, NB=4 batches/block, 512 blocks -> 2 blocks/CU.
// KEY HYPOTHESIS: two co-resident INDEPENDENT blocks interleave their serial
// chains (separate barriers), unlike same-block waves (R3 disproof).
// Wave w owns hidden units 16w..16w+15. Batch rows 0-3 of the MFMA tile are
// real; rows 4-15 zero. After MFMA, rows are spread so lane 16r+c owns the
// single (batch r, unit 16w+c) pair -> 8 trans instr/wave/step.
__global__ __launch_bounds__(256, 1) void lstm_kernel(
    const float* __restrict__ x, const float* __restrict__ w_ih,
    const float* __restrict__ w_hh, const float* __restrict__ b_ih,
    const float* __restrict__ b_hh, const float* __restrict__ w_fc,
    const float* __restrict__ b_fc, float* __restrict__ out)
{
    __shared__ __align__(16) unsigned short hbuf[2][16 * HSTRIDE];  // 4.6 KB
    __shared__ __align__(16) _Float16 xls[NB * XSTRIDE];            // 4.2 KB
    __shared__ __align__(16) float ols[NB * OSTRIDE];               // 8.2 KB

    const int tid  = threadIdx.x;
    const int w    = tid >> 6;        // wave 0..3
    const int lane = tid & 63;
    const int qq   = lane >> 4;       // A-frag k-quad
    const int c    = lane & 15;       // unit-in-tile / A-row
    const int row  = lane >> 4;       // after spread: this lane's batch row (0..3)
    const bool h16 = (lane >> 4) & 1;
    const bool h32 = (lane >> 5) & 1;
    const int b0   = blockIdx.x * NB;

    // ---- stage x: global -> LDS (fp16), coalesced float4 reads ----
    for (int i = tid; i < NB * 128; i += 256) {      // 4 rows x 128 float4
        int b  = i >> 7;
        int t4 = i & 127;
        float4 v = *(const float4*)(x + (size_t)(b0 + b) * T_STEPS + t4 * 4);
        half4 hv;
        hv[0] = (_Float16)v.x; hv[1] = (_Float16)v.y;
        hv[2] = (_Float16)v.z; hv[3] = (_Float16)v.w;
        *(half4*)(&xls[b * XSTRIDE + t4 * 4]) = hv;
    }
    // zero BOTH h buffers; rows 4-15 stay zero forever (A-row padding)
    for (int i = tid; i < 2 * 16 * HSTRIDE; i += 256)
        ((unsigned short*)hbuf)[i] = 0;

    // ---- B fragments (weights) in VGPRs: tile n = gate class, K-frag kk ----
    short8 bfrag[4][2];
    float bias_n[4], wih_n[4];
#pragma unroll
    for (int n = 0; n < 4; ++n) {
        int g = 64 * n + 16 * w + c;
        bias_n[n] = b_ih[g] + b_hh[g];
        wih_n[n]  = w_ih[g];
#pragma unroll
        for (int kk = 0; kk < 2; ++kk) {
            const float* wp = w_hh + g * 64 + 32 * kk + 8 * qq;
            float4 lo  = *(const float4*)(wp);
            float4 hi4 = *(const float4*)(wp + 4);
            short8 f;
            f[0] = (short)f2bf(lo.x);  f[1] = (short)f2bf(lo.y);
            f[2] = (short)f2bf(lo.z);  f[3] = (short)f2bf(lo.w);
            f[4] = (short)f2bf(hi4.x); f[5] = (short)f2bf(hi4.y);
            f[6] = (short)f2bf(hi4.z); f[7] = (short)f2bf(hi4.w);
            bfrag[n][kk] = f;
        }
    }

    // fc weights aligned to this lane's A-fragment k-slice
    float wfc0[8], wfc1[8];
#pragma unroll
    for (int j = 0; j < 8; ++j) { wfc0[j] = w_fc[8 * qq + j]; wfc1[j] = w_fc[32 + 8 * qq + j]; }
    const float bfc = b_fc[0];

    float cs = 0.f;             // fp32 cell state for (batch row, unit 16w+c)

    __syncthreads();

    short8 sa0 = {}, sa1 = {};  // saved A-frags for rotated fc-dot

    for (int tq = 0; tq < 128; ++tq) {
        // this lane's own batch row x values for the quad (broadcast read)
        half4 hx = *(const half4*)(&xls[row * XSTRIDE + tq * 4]);
        float xv[4] = {(float)hx[0], (float)hx[1], (float)hx[2], (float)hx[3]};

#pragma unroll
        for (int dt = 0; dt < 4; ++dt) {
            const int t  = tq * 4 + dt;
            const int rb = t & 1;
            const unsigned short* hrd = hbuf[rb];

            // A-frags: A[m=c][k=32kk+8qq+j] of h_{t-1}; rows c>=4 are zero
            short8 a0 = *(const short8*)(hrd + c * HSTRIDE + 8 * qq);
            short8 a1 = *(const short8*)(hrd + c * HSTRIDE + 32 + 8 * qq);

            if (dt == w) { sa0 = a0; sa1 = a1; }   // rotate fc-dot ownership

            // C-init = bias (constant over rows); x-term folded in after spread
            f32x4 acc[4];
#pragma unroll
            for (int n = 0; n < 4; ++n) {
                f32x4 a;
                a[0] = bias_n[n]; a[1] = bias_n[n]; a[2] = bias_n[n]; a[3] = bias_n[n];
                acc[n] = __builtin_amdgcn_mfma_f32_16x16x32_bf16(a0, bfrag[n][0], a, 0, 0, 0);
                acc[n] = __builtin_amdgcn_mfma_f32_16x16x32_bf16(a1, bfrag[n][1], acc[n], 0, 0, 0);
            }

            // spread: lane 16r+c <- acc[n][r] of lane c  (rows live in lanes 0-15)
            float v[4];
#pragma unroll
            for (int n = 0; n < 4; ++n) {
                float s1 = __shfl_xor(acc[n][1], 16);
                float w0 = h16 ? s1 : acc[n][0];      // lanes 0-31: rows 0/1
                float s3 = __shfl_xor(acc[n][3], 16);
                float w1 = h16 ? s3 : acc[n][2];      // lanes 0-31: rows 2/3
                float s5 = __shfl_xor(w1, 32);
                float vv = h32 ? s5 : w0;             // all lanes: row = lane>>4
                v[n] = fmaf(xv[dt], wih_n[n], vv);    // + x*w_ih
            }

            // fused activations; this lane owns (batch row, unit 16w+c)
            {
                float A  = ex2(v[0] * -K1);
                float B  = ex2(v[2] *  K2);
                float ig = (B - 1.0f) * rcp_fast((1.0f + A) * (1.0f + B));
                float rf = rcp_fast(1.0f + ex2(v[1] * -K1));
                cs = fmaf(cs, rf, ig);
                float cc = fminf(fmaxf(cs, -15.f), 15.f);
                float Ao = ex2(v[3] * -K1);
                float C  = ex2(cc *  K2);
                float h  = (C - 1.0f) * rcp_fast((1.0f + Ao) * (1.0f + C));
                hbuf[rb ^ 1][row * HSTRIDE + 16 * w + c] = f2bf(h);
            }
            __syncthreads();
        }

        // rotated fc-dot: saved frag is A of step st = tq*4+w = h_{st-1}
        {
            int st = tq * 4 + w;
            if (st > 0) {
                float s = out_dot(sa0, sa1, wfc0, wfc1);
                if (lane < NB) ols[lane * OSTRIDE + (st - 1)] = s + bfc;
            }
        }
    }

    // final output column: h_511 lives in hbuf[0]
    if (w == 3) {
        const unsigned short* hrd = hbuf[0];
        short8 a0 = *(const short8*)(hrd + c * HSTRIDE + 8 * qq);
        short8 a1 = *(const short8*)(hrd + c * HSTRIDE + 32 + 8 * qq);
        float s = out_dot(a0, a1, wfc0, wfc1);
        if (lane < NB) ols[lane * OSTRIDE + (T_STEPS - 1)] = s + bfc;
    }
    __syncthreads();

    // bulk store: LDS out -> global, coalesced
    for (int i = tid; i < NB * T_STEPS; i += 256) {
        int b = i >> 9;
        int t = i & (T_STEPS - 1);
        out[(size_t)(b0 + b) * T_STEPS + t] = ols[b * OSTRIDE + t];
    }
}

extern "C" void kernel_launch(void* const* d_in, const int* in_sizes, int n_in,
                              void* d_out, int out_size, void* d_ws, size_t ws_size,
                              hipStream_t stream) {
    const float* x    = (const float*)d_in[0];
    const float* w_ih = (const float*)d_in[1];
    const float* w_hh = (const float*)d_in[2];
    const float* b_ih = (const float*)d_in[3];
    const float* b_hh = (const float*)d_in[4];
    const float* w_fc = (const float*)d_in[5];
    const float* b_fc = (const float*)d_in[6];
    float* out = (float*)d_out;
    hipLaunchKernelGGL(lstm_kernel, dim3(2048 / NB), dim3(256), 0, stream,
                       x, w_ih, w_hh, b_ih, b_hh, w_fc, b_fc, out);
}